// Round 2
// baseline (352.356 us; speedup 1.0000x reference)
//
#include <hip/hip_runtime.h>

// Problem constants (fixed by reference)
#define T_SEQ 1024
#define BATCH 8
#define DMODEL 1024
#define NHEAD 16
#define HDIM 64
#define M_ROWS (T_SEQ * BATCH)   // 8192
// attention scale 0.125 with log2(e) folded in (exp -> exp2)
#define QSCALE (0.125f * 1.44269504088896f)

typedef unsigned short ushort_t;
typedef __attribute__((ext_vector_type(8))) short short8;   // 8 bf16 = 4 VGPRs (MFMA A/B frag)
typedef __attribute__((ext_vector_type(4))) float f32x4;    // MFMA C/D frag

// async global->LDS, 16B per lane; LDS dest = wave-uniform base + lane*16
#define G2L16(g, l) __builtin_amdgcn_global_load_lds(                      \
    (const __attribute__((address_space(1))) void*)(g),                    \
    (__attribute__((address_space(3))) void*)(l), 16, 0, 0)

#define SBAR()  __builtin_amdgcn_s_barrier()
#define LGKM0() asm volatile("s_waitcnt lgkmcnt(0)" ::: "memory")

// f32 -> bf16 round-to-nearest-even (finite inputs only)
static __device__ __forceinline__ ushort_t f2bf(float f) {
    unsigned int u = __builtin_bit_cast(unsigned int, f);
    u += 0x7FFFu + ((u >> 16) & 1u);
    return (ushort_t)(u >> 16);
}

// pack two f32 -> bf16x2 (lo in [15:0], hi in [31:16]), RNE
#if __has_builtin(__builtin_amdgcn_cvt_pk_bf16_f32)
typedef __attribute__((ext_vector_type(2))) __bf16 bf16x2_t;
static __device__ __forceinline__ unsigned pk2(float lo, float hi) {
    bf16x2_t r = __builtin_amdgcn_cvt_pk_bf16_f32(lo, hi);
    return __builtin_bit_cast(unsigned, r);
}
#else
static __device__ __forceinline__ unsigned pk2(float lo, float hi) {
    return (unsigned)f2bf(lo) | ((unsigned)f2bf(hi) << 16);
}
#endif

// raw v_exp_f32 (2^x)
#if __has_builtin(__builtin_amdgcn_exp2f)
#define EXP2F(x) __builtin_amdgcn_exp2f(x)
#else
#define EXP2F(x) exp2f(x)
#endif

// ---------------------------------------------------------------------------
// Fused f32 -> bf16 cast of all 7 tensors: grid.y selects tensor.
// y 0..2: big (q,k,v inputs), y 3..6: small (Wq,Wk,Wv,Wo).
// ---------------------------------------------------------------------------
__global__ __launch_bounds__(256) void cast_all_bf16(
    const float4* __restrict__ s0, const float4* __restrict__ s1,
    const float4* __restrict__ s2, const float4* __restrict__ s3,
    const float4* __restrict__ s4, const float4* __restrict__ s5,
    const float4* __restrict__ s6,
    uint2* __restrict__ d0, uint2* __restrict__ d1, uint2* __restrict__ d2,
    uint2* __restrict__ d3, uint2* __restrict__ d4, uint2* __restrict__ d5,
    uint2* __restrict__ d6, int n4big, int n4small)
{
    const int y = blockIdx.y;
    const int n4 = (y < 3) ? n4big : n4small;
    const int i = blockIdx.x * 256 + threadIdx.x;
    if (i >= n4) return;
    const float4* s; uint2* d;
    switch (y) {
        case 0: s = s0; d = d0; break;
        case 1: s = s1; d = d1; break;
        case 2: s = s2; d = d2; break;
        case 3: s = s3; d = d3; break;
        case 4: s = s4; d = d4; break;
        case 5: s = s5; d = d5; break;
        default: s = s6; d = d6; break;
    }
    float4 v = s[i];
    uint2 o; o.x = pk2(v.x, v.y); o.y = pk2(v.z, v.w);
    d[i] = o;
}

// ---------------------------------------------------------------------------
// 256x256 8-wave 8-phase MFMA GEMM: Y[M,N] = A[M,K](bf16) @ W[N,K](bf16)^T + b.
// BK=64, double-buffered LDS (128 KiB), counted-vmcnt pipeline:
//   phase P1: stage A-half0(T+1), read A(ih=0)+B(jh=0) frags, MFMA Q(0,0)
//   phase P2: stage A-half1(T+1), read B(jh=1) frags,        MFMA Q(0,1)
//   phase P3: stage B-half0(T+2), read A(ih=1) frags,        MFMA Q(1,0)
//   phase P4: stage B-half1(T+2),                            MFMA Q(1,1)
//             s_waitcnt vmcnt(4)  <- drains A(T+1)+B(T+1); leaves B(T+2) live
// B(T+2) overwrites B(T)'s slots, which die after P2 (barrier-separated).
// Raw s_barrier (NOT __syncthreads -> no implicit vmcnt(0) drain), lgkmcnt(0)
// before each barrier, setprio around MFMA clusters, chunk-XOR LDS swizzle
// (slot c at row r holds global chunk c^(r&7); conflict-free, verified).
// Grid: x = N/256 (must be 4), y = M/256. Bijective XCD-chunked swizzle
// (requires nwg % 8 == 0; 384 and 128 both qualify).
// Multi-segment: sel = bmg>>5 picks weight/bias (QKV fusion, 32 blocks/seg).
// ---------------------------------------------------------------------------
template<bool OUT_BF16>
__global__ __launch_bounds__(512) void gemm256_bt(
    const ushort_t* __restrict__ A, const ushort_t* __restrict__ Wbase,
    const float* __restrict__ bias0, const float* __restrict__ bias1,
    const float* __restrict__ bias2, void* __restrict__ Yv,
    int N, int K, float scale0)
{
    __shared__ ushort_t As[2][256 * 64];   // 64 KiB
    __shared__ ushort_t Bs[2][256 * 64];   // 64 KiB

    const int tid  = threadIdx.x;
    const int lane = tid & 63;
    const int w    = tid >> 6;        // 0..7
    const int wm   = w >> 2;          // 0..1 -> 128-row half
    const int wn   = w & 3;           // 0..3 -> 64-col slice
    const int quad = lane >> 4;
    const int l16  = lane & 15;
    const int srow = lane >> 3;       // 0..7 within 8-row segment
    const int sch  = lane & 7;        // chunk slot 0..7

    // bijective XCD-chunked block swizzle
    const int nwg = gridDim.x * gridDim.y;
    const int lin = blockIdx.y * gridDim.x + blockIdx.x;
    const int qq  = nwg >> 3;
    const int swz = (lin & 7) * qq + (lin >> 3);
    const int bn  = swz & 3;          // gridDim.x == 4 (N = 1024)
    const int bmg = swz >> 2;

    const int sel = bmg >> 5;         // 32 blocks per 8192-row segment
    const ushort_t* Wb = Wbase + (size_t)sel * N * K;
    const float* bias = (sel == 0) ? bias0 : (sel == 1) ? bias1 : bias2;
    const float scale = (sel == 0) ? scale0 : 1.0f;

    const size_t arow0 = (size_t)bmg * 256;
    const size_t brow0 = (size_t)bn * 256;
    const int scol = (sch ^ srow) * 8;       // pre-swizzled source chunk

    // per-(half,seg) staging base offsets (elements)
    size_t aoff[2][2], boff[2][2];
#pragma unroll
    for (int h = 0; h < 2; h++)
#pragma unroll
        for (int u = 0; u < 2; u++) {
            const int rl = h * 128 + (w * 2 + u) * 8 + srow;
            aoff[h][u] = (arow0 + rl) * (size_t)K + scol;
            boff[h][u] = (brow0 + rl) * (size_t)K + scol;
        }

    // frag-read chunk offsets: ks=0 -> c0, ks=1 -> c0^32 (chunk^(4))
    const int c0 = (quad ^ (l16 & 7)) * 8;
    const int c1 = c0 ^ 32;

    const f32x4 zero4 = {0.f, 0.f, 0.f, 0.f};
    f32x4 acc[8][4];
#pragma unroll
    for (int i = 0; i < 8; i++)
#pragma unroll
        for (int j = 0; j < 4; j++) acc[i][j] = zero4;

    short8 af[4][2];        // current A ih-half frags [ii][ks]
    short8 bfx[2][2][2];    // B frags [jh][jj][ks], both halves live

    const int nT = K >> 6;  // 16

#define STAGE_A(t, buf, h)                                                  \
    do {                                                                    \
        G2L16(A + aoff[h][0] + (t) * 64,                                    \
              (char*)&As[buf][0] + (h) * 16384 + (w * 2 + 0) * 1024);       \
        G2L16(A + aoff[h][1] + (t) * 64,                                    \
              (char*)&As[buf][0] + (h) * 16384 + (w * 2 + 1) * 1024);       \
    } while (0)
#define STAGE_B(t, buf, h)                                                  \
    do {                                                                    \
        G2L16(Wb + boff[h][0] + (t) * 64,                                   \
              (char*)&Bs[buf][0] + (h) * 16384 + (w * 2 + 0) * 1024);       \
        G2L16(Wb + boff[h][1] + (t) * 64,                                   \
              (char*)&Bs[buf][0] + (h) * 16384 + (w * 2 + 1) * 1024);       \
    } while (0)

    // ---- prologue: tile0 (A0,A1,B0,B1) + tile1 (B0,B1); prime vmcnt ----
    STAGE_A(0, 0, 0); STAGE_A(0, 0, 1);
    STAGE_B(0, 0, 0); STAGE_B(0, 0, 1);
    STAGE_B(1, 1, 0); STAGE_B(1, 1, 1);
    asm volatile("s_waitcnt vmcnt(4)" ::: "memory");   // tile0 drained; B(1) in flight
    SBAR();

    for (int kt = 0; kt < nT; ++kt) {
        const int cur = kt & 1;

        // ---- P1: stage A0(kt+1); read A(ih=0)+B(jh=0); MFMA Q(0,0) ----
        if (kt + 1 < nT) STAGE_A(kt + 1, cur ^ 1, 0);
#pragma unroll
        for (int ii = 0; ii < 4; ii++) {
            const int row = wm * 128 + ii * 16 + l16;
            af[ii][0] = *(const short8*)&As[cur][row * 64 + c0];
            af[ii][1] = *(const short8*)&As[cur][row * 64 + c1];
        }
#pragma unroll
        for (int jj = 0; jj < 2; jj++) {
            const int row = wn * 64 + jj * 16 + l16;
            bfx[0][jj][0] = *(const short8*)&Bs[cur][row * 64 + c0];
            bfx[0][jj][1] = *(const short8*)&Bs[cur][row * 64 + c1];
        }
        __builtin_amdgcn_s_setprio(1);
#pragma unroll
        for (int ii = 0; ii < 4; ii++)
#pragma unroll
            for (int jj = 0; jj < 2; jj++)
#pragma unroll
                for (int ks = 0; ks < 2; ks++)
                    acc[ii][jj] = __builtin_amdgcn_mfma_f32_16x16x32_bf16(
                        af[ii][ks], bfx[0][jj][ks], acc[ii][jj], 0, 0, 0);
        __builtin_amdgcn_s_setprio(0);
        LGKM0();
        SBAR();

        // ---- P2: stage A1(kt+1); read B(jh=1); MFMA Q(0,1) ----
        if (kt + 1 < nT) STAGE_A(kt + 1, cur ^ 1, 1);
#pragma unroll
        for (int jj = 0; jj < 2; jj++) {
            const int row = wn * 64 + 32 + jj * 16 + l16;
            bfx[1][jj][0] = *(const short8*)&Bs[cur][row * 64 + c0];
            bfx[1][jj][1] = *(const short8*)&Bs[cur][row * 64 + c1];
        }
        __builtin_amdgcn_s_setprio(1);
#pragma unroll
        for (int ii = 0; ii < 4; ii++)
#pragma unroll
            for (int jj = 0; jj < 2; jj++)
#pragma unroll
                for (int ks = 0; ks < 2; ks++)
                    acc[ii][2 + jj] = __builtin_amdgcn_mfma_f32_16x16x32_bf16(
                        af[ii][ks], bfx[1][jj][ks], acc[ii][2 + jj], 0, 0, 0);
        __builtin_amdgcn_s_setprio(0);
        LGKM0();
        SBAR();

        // ---- P3: stage B0(kt+2) over dead B(kt)h0; read A(ih=1); MFMA Q(1,0) ----
        if (kt + 2 < nT) STAGE_B(kt + 2, cur, 0);
#pragma unroll
        for (int ii = 0; ii < 4; ii++) {
            const int row = wm * 128 + 64 + ii * 16 + l16;
            af[ii][0] = *(const short8*)&As[cur][row * 64 + c0];
            af[ii][1] = *(const short8*)&As[cur][row * 64 + c1];
        }
        __builtin_amdgcn_s_setprio(1);
#pragma unroll
        for (int ii = 0; ii < 4; ii++)
#pragma unroll
            for (int jj = 0; jj < 2; jj++)
#pragma unroll
                for (int ks = 0; ks < 2; ks++)
                    acc[4 + ii][jj] = __builtin_amdgcn_mfma_f32_16x16x32_bf16(
                        af[ii][ks], bfx[0][jj][ks], acc[4 + ii][jj], 0, 0, 0);
        __builtin_amdgcn_s_setprio(0);
        LGKM0();
        SBAR();

        // ---- P4: stage B1(kt+2); MFMA Q(1,1); counted vmcnt ----
        if (kt + 2 < nT) STAGE_B(kt + 2, cur, 1);
        __builtin_amdgcn_s_setprio(1);
#pragma unroll
        for (int ii = 0; ii < 4; ii++)
#pragma unroll
            for (int jj = 0; jj < 2; jj++)
#pragma unroll
                for (int ks = 0; ks < 2; ks++)
                    acc[4 + ii][2 + jj] = __builtin_amdgcn_mfma_f32_16x16x32_bf16(
                        af[ii][ks], bfx[1][jj][ks], acc[4 + ii][2 + jj], 0, 0, 0);
        __builtin_amdgcn_s_setprio(0);
        LGKM0();
        if (kt < nT - 2) asm volatile("s_waitcnt vmcnt(4)" ::: "memory");
        else             asm volatile("s_waitcnt vmcnt(0)" ::: "memory");
        SBAR();
    }
#undef STAGE_A
#undef STAGE_B

    // ---- epilogue: bias + scale, store ----
    float bj[4];
#pragma unroll
    for (int j = 0; j < 4; j++) bj[j] = bias[bn * 256 + wn * 64 + j * 16 + l16];
#pragma unroll
    for (int il = 0; il < 8; il++) {
#pragma unroll
        for (int r = 0; r < 4; r++) {
            const size_t row = (size_t)bmg * 256 + wm * 128 + il * 16 + quad * 4 + r;
#pragma unroll
            for (int j = 0; j < 4; j++) {
                const int col = bn * 256 + wn * 64 + j * 16 + l16;
                const float v = (acc[il][j][r] + bj[j]) * scale;
                if (OUT_BF16) ((ushort_t*)Yv)[row * N + col] = f2bf(v);
                else          ((float*)   Yv)[row * N + col] = v;
            }
        }
    }
}

// ---------------------------------------------------------------------------
// Vp (T,B,H,HD) bf16 -> Vt (B,H,HD,T) bf16  (64x64 tiles through LDS)
// ---------------------------------------------------------------------------
__global__ __launch_bounds__(256) void transpose_v(
    const ushort_t* __restrict__ Vp, ushort_t* __restrict__ Vt)
{
    __shared__ ushort_t Ts[64][72];
    const int tid = threadIdx.x;
    const int t0 = blockIdx.x * 64;
    const int bh = blockIdx.y;
    const int b = bh >> 4, h = bh & 15;

#pragma unroll
    for (int u = 0; u < 2; u++) {
        int e = u * 256 + tid;          // 512 chunks of 8 bf16
        int row = e >> 3, ch = (e & 7) * 8;
        uint4 v = *(const uint4*)&Vp[((size_t)(t0 + row) * BATCH + b) * DMODEL + h * 64 + ch];
        *(uint4*)&Ts[row][ch] = v;
    }
    __syncthreads();
#pragma unroll
    for (int u = 0; u < 2; u++) {
        int e = u * 256 + tid;
        int d = e >> 3, tc = (e & 7) * 8;
        uint4 o;
        o.x = (unsigned)Ts[tc + 0][d] | ((unsigned)Ts[tc + 1][d] << 16);
        o.y = (unsigned)Ts[tc + 2][d] | ((unsigned)Ts[tc + 3][d] << 16);
        o.z = (unsigned)Ts[tc + 4][d] | ((unsigned)Ts[tc + 5][d] << 16);
        o.w = (unsigned)Ts[tc + 6][d] | ((unsigned)Ts[tc + 7][d] << 16);
        *(uint4*)&Vt[((size_t)(bh * 64 + d)) * T_SEQ + t0 + tc] = o;
    }
}

// ---------------------------------------------------------------------------
// MFMA flash attention, S^T formulation (unchanged this round).
// ---------------------------------------------------------------------------
__global__ __launch_bounds__(256) void attn_mfma(
    const ushort_t* __restrict__ Qp, const ushort_t* __restrict__ Kp,
    const ushort_t* __restrict__ VtG, ushort_t* __restrict__ Ao)
{
    __shared__ ushort_t Ks[64 * 64];     // [s][hd], 128B rows, 8 chunks, swizzled
    __shared__ ushort_t Vs[64 * 64];     // [hd][s], same structure
    __shared__ ushort_t Pl[4][32][72];   // per-wave P / O-bounce, pitch 72

    const int tid  = threadIdx.x;
    const int lane = tid & 63;
    const int w    = tid >> 6;
    const int quad = lane >> 4;
    const int l16  = lane & 15;
    const int bid  = blockIdx.x;
    const int qb   = bid >> 7;          // 0..7
    const int bh   = bid & 127;
    const int b    = bh >> 4, h = bh & 15;
    const int hoff = h * 64;
    const int q0   = qb * 128 + w * 32;  // this wave's 32 Q rows

    const int srow_in = lane >> 3;       // 0..7 within 8-row segment
    const int sch     = lane & 7;

    // Q fragments (B-operand; same layout as A), in registers all kernel
    short8 qf[2][2];
#pragma unroll
    for (int rt = 0; rt < 2; rt++)
#pragma unroll
        for (int ks = 0; ks < 2; ks++)
            qf[rt][ks] = *(const short8*)&Qp[((size_t)(q0 + rt * 16 + l16) * BATCH + b) * DMODEL
                                             + hoff + ks * 32 + quad * 8];

    short8 ones;
#pragma unroll
    for (int i = 0; i < 8; i++) ones[i] = (short)0x3F80;   // bf16 1.0

    const f32x4 zero4 = {0.f, 0.f, 0.f, 0.f};
    f32x4 oacc[2][4], lacc[2];
#pragma unroll
    for (int rt = 0; rt < 2; rt++) {
        lacc[rt] = zero4;
#pragma unroll
        for (int c = 0; c < 4; c++) oacc[rt][c] = zero4;
    }

    for (int s0 = 0; s0 < T_SEQ; s0 += 64) {
        __syncthreads();   // prev iteration done reading Ks/Vs
#pragma unroll
        for (int u = 0; u < 2; u++) {
            int seg = w * 2 + u;                 // 0..7
            int row = seg * 8 + srow_in;         // 0..63
            int chs = sch ^ (row & 7);
            G2L16(&Kp[((size_t)(s0 + row) * BATCH + b) * DMODEL + hoff + chs * 8],
                  (char*)Ks + seg * 1024);
            G2L16(&VtG[((size_t)(bh * 64 + row)) * T_SEQ + s0 + chs * 8],
                  (char*)Vs + seg * 1024);
        }
        __syncthreads();   // DMA drained

        // ---- S^T = K . Q^T : per c-tile D[m=s in c*16..][n=q] ----
        f32x4 sacc[2][4];
#pragma unroll
        for (int rt = 0; rt < 2; rt++)
#pragma unroll
            for (int c = 0; c < 4; c++) sacc[rt][c] = zero4;
#pragma unroll
        for (int c = 0; c < 4; c++) {
            int row = c * 16 + l16;
#pragma unroll
            for (int ks = 0; ks < 2; ks++) {
                short8 kf = *(const short8*)&Ks[row * 64 + (((ks * 4 + quad) ^ (row & 7)) * 8)];
#pragma unroll
                for (int rt = 0; rt < 2; rt++)
                    sacc[rt][c] = __builtin_amdgcn_mfma_f32_16x16x32_bf16(
                        kf, qf[rt][ks], sacc[rt][c], 0, 0, 0);
            }
        }

        // ---- P = exp2(S): packed b64 writes, already B-fragment layout ----
#pragma unroll
        for (int rt = 0; rt < 2; rt++)
#pragma unroll
            for (int c = 0; c < 4; c++) {
                uint2 pv;
                pv.x = pk2(EXP2F(sacc[rt][c][0]), EXP2F(sacc[rt][c][1]));
                pv.y = pk2(EXP2F(sacc[rt][c][2]), EXP2F(sacc[rt][c][3]));
                *(uint2*)&Pl[w][rt * 16 + l16][c * 16 + quad * 4] = pv;
            }

        short8 pf[2][2];
#pragma unroll
        for (int rt = 0; rt < 2; rt++)
#pragma unroll
            for (int ks = 0; ks < 2; ks++)
                pf[rt][ks] = *(const short8*)&Pl[w][rt * 16 + l16][ks * 32 + quad * 8];

        // ---- denominator: lacc[n=q] += sum_s P[q][s] ----
#pragma unroll
        for (int rt = 0; rt < 2; rt++)
#pragma unroll
            for (int ks = 0; ks < 2; ks++)
                lacc[rt] = __builtin_amdgcn_mfma_f32_16x16x32_bf16(
                    ones, pf[rt][ks], lacc[rt], 0, 0, 0);

        // ---- O^T += V^T . P^T : D[m=d][n=q] ----
#pragma unroll
        for (int dt = 0; dt < 4; dt++) {
            int row = dt * 16 + l16;
#pragma unroll
            for (int ks = 0; ks < 2; ks++) {
                short8 vf = *(const short8*)&Vs[row * 64 + (((ks * 4 + quad) ^ (row & 7)) * 8)];
#pragma unroll
                for (int rt = 0; rt < 2; rt++)
                    oacc[rt][dt] = __builtin_amdgcn_mfma_f32_16x16x32_bf16(
                        vf, pf[rt][ks], oacc[rt][dt], 0, 0, 0);
            }
        }
    }

    // ---- normalize (per-lane, no shuffles), bounce through Pl, store ----
#pragma unroll
    for (int rt = 0; rt < 2; rt++) {
        float inv = 1.f / lacc[rt][0];   // all 4 regs identical (A=ones)
#pragma unroll
        for (int dt = 0; dt < 4; dt++) {
            uint2 ov;
            ov.x = pk2(oacc[rt][dt][0] * inv, oacc[rt][dt][1] * inv);
            ov.y = pk2(oacc[rt][dt][2] * inv, oacc[rt][dt][3] * inv);
            *(uint2*)&Pl[w][rt * 16 + l16][dt * 16 + quad * 4] = ov;
        }
    }
    // coalesced 16B stores: 8 lanes cover one 128B row
#pragma unroll
    for (int it = 0; it < 4; it++) {
        int row = it * 8 + (lane >> 3);
        int ch  = lane & 7;
        uint4 val = *(const uint4*)&Pl[w][row][ch * 8];
        *(uint4*)&Ao[((size_t)(q0 + row) * BATCH + b) * DMODEL + hoff + ch * 8] = val;
    }
}

// ---------------------------------------------------------------------------
extern "C" void kernel_launch(void* const* d_in, const int* in_sizes, int n_in,
                              void* d_out, int out_size, void* d_ws, size_t ws_size,
                              hipStream_t stream)
{
    const float* q  = (const float*)d_in[0];
    const float* k  = (const float*)d_in[1];
    const float* v  = (const float*)d_in[2];
    const float* Wq = (const float*)d_in[3];
    const float* bq = (const float*)d_in[4];
    const float* Wk = (const float*)d_in[5];
    const float* bk = (const float*)d_in[6];
    const float* Wv = (const float*)d_in[7];
    const float* bv = (const float*)d_in[8];
    const float* Wo = (const float*)d_in[9];
    const float* bo = (const float*)d_in[10];

    // workspace layout (bf16 elems). qb..vb contiguous (stacked QKV-GEMM A),
    // Qp..Vp contiguous (stacked output), Wqb..Wob contiguous (sel-indexed).
    // Vt aliases qb (dead after QKV-GEMM), Aob aliases kb. Total 109 MB.
    ushort_t* ws = (ushort_t*)d_ws;
    const size_t E = (size_t)M_ROWS * DMODEL;    // 8388608
    const size_t EW = (size_t)DMODEL * DMODEL;   // 1048576
    ushort_t* qb  = ws;            // input q bf16; reused as Vt
    ushort_t* kb  = ws + E;        // input k bf16; reused as Aob
    ushort_t* vb  = ws + 2 * E;
    ushort_t* Qp  = ws + 3 * E;
    ushort_t* Kp  = ws + 4 * E;
    ushort_t* Vp  = ws + 5 * E;
    ushort_t* Wqb = ws + 6 * E;
    ushort_t* Wkb = Wqb + EW;
    ushort_t* Wvb = Wkb + EW;
    ushort_t* Wob = Wvb + EW;
    ushort_t* Vt  = qb;
    ushort_t* Aob = kb;

    const int n4_in = (int)(E / 4);   // 2097152
    const int n4_w  = (int)(EW / 4);  // 262144
    cast_all_bf16<<<dim3(n4_in / 256, 7), 256, 0, stream>>>(
        (const float4*)q, (const float4*)k, (const float4*)v,
        (const float4*)Wq, (const float4*)Wk, (const float4*)Wv, (const float4*)Wo,
        (uint2*)qb, (uint2*)kb, (uint2*)vb,
        (uint2*)Wqb, (uint2*)Wkb, (uint2*)Wvb, (uint2*)Wob,
        n4_in, n4_w);

    // fused QKV projection: M = 3*8192 -> 96 row-blocks, sel = bmg>>5.
    // Q-segment scale = 0.125*log2(e) (exp2 trick downstream).
    gemm256_bt<true><<<dim3(DMODEL / 256, 3 * M_ROWS / 256), 512, 0, stream>>>(
        qb, Wqb, bq, bk, bv, Qp, DMODEL, DMODEL, QSCALE);

    transpose_v<<<dim3(T_SEQ / 64, BATCH * NHEAD), 256, 0, stream>>>(Vp, Vt);

    attn_mfma<<<dim3(8 * 128), 256, 0, stream>>>(Qp, Kp, Vt, Aob);

    gemm256_bt<false><<<dim3(DMODEL / 256, M_ROWS / 256), 512, 0, stream>>>(
        Aob, Wob, bo, bo, bo, d_out, DMODEL, DMODEL, 1.0f);
}

// Round 3
// 319.202 us; speedup vs baseline: 1.1039x; 1.1039x over previous
//
#include <hip/hip_runtime.h>

// Problem constants (fixed by reference)
#define T_SEQ 1024
#define BATCH 8
#define DMODEL 1024
#define NHEAD 16
#define HDIM 64
#define M_ROWS (T_SEQ * BATCH)   // 8192
// attention scale 0.125 with log2(e) folded in (exp -> exp2)
#define QSCALE (0.125f * 1.44269504088896f)

typedef unsigned short ushort_t;
typedef __attribute__((ext_vector_type(8))) short short8;   // 8 bf16 = 4 VGPRs (MFMA A/B frag)
typedef __attribute__((ext_vector_type(4))) float f32x4;    // MFMA C/D frag

// async global->LDS, 16B per lane; LDS dest = wave-uniform base + lane*16
#define G2L16(g, l) __builtin_amdgcn_global_load_lds(                      \
    (const __attribute__((address_space(1))) void*)(g),                    \
    (__attribute__((address_space(3))) void*)(l), 16, 0, 0)

#define SBAR()  __builtin_amdgcn_s_barrier()
#define LGKM0() asm volatile("s_waitcnt lgkmcnt(0)" ::: "memory")

// f32 -> bf16 round-to-nearest-even (finite inputs only)
static __device__ __forceinline__ ushort_t f2bf(float f) {
    unsigned int u = __builtin_bit_cast(unsigned int, f);
    u += 0x7FFFu + ((u >> 16) & 1u);
    return (ushort_t)(u >> 16);
}

// pack two f32 -> bf16x2 (lo in [15:0], hi in [31:16]), RNE
#if __has_builtin(__builtin_amdgcn_cvt_pk_bf16_f32)
typedef __attribute__((ext_vector_type(2))) __bf16 bf16x2_t;
static __device__ __forceinline__ unsigned pk2(float lo, float hi) {
    bf16x2_t r = __builtin_amdgcn_cvt_pk_bf16_f32(lo, hi);
    return __builtin_bit_cast(unsigned, r);
}
#else
static __device__ __forceinline__ unsigned pk2(float lo, float hi) {
    return (unsigned)f2bf(lo) | ((unsigned)f2bf(hi) << 16);
}
#endif

// raw v_exp_f32 (2^x)
#if __has_builtin(__builtin_amdgcn_exp2f)
#define EXP2F(x) __builtin_amdgcn_exp2f(x)
#else
#define EXP2F(x) exp2f(x)
#endif

// ---------------------------------------------------------------------------
// Fused f32 -> bf16 cast of all 7 tensors: grid.y selects tensor.
// ---------------------------------------------------------------------------
__global__ __launch_bounds__(256) void cast_all_bf16(
    const float4* __restrict__ s0, const float4* __restrict__ s1,
    const float4* __restrict__ s2, const float4* __restrict__ s3,
    const float4* __restrict__ s4, const float4* __restrict__ s5,
    const float4* __restrict__ s6,
    uint2* __restrict__ d0, uint2* __restrict__ d1, uint2* __restrict__ d2,
    uint2* __restrict__ d3, uint2* __restrict__ d4, uint2* __restrict__ d5,
    uint2* __restrict__ d6, int n4big, int n4small)
{
    const int y = blockIdx.y;
    const int n4 = (y < 3) ? n4big : n4small;
    const int i = blockIdx.x * 256 + threadIdx.x;
    if (i >= n4) return;
    const float4* s; uint2* d;
    switch (y) {
        case 0: s = s0; d = d0; break;
        case 1: s = s1; d = d1; break;
        case 2: s = s2; d = d2; break;
        case 3: s = s3; d = d3; break;
        case 4: s = s4; d = d4; break;
        case 5: s = s5; d = d5; break;
        default: s = s6; d = d6; break;
    }
    float4 v = s[i];
    uint2 o; o.x = pk2(v.x, v.y); o.y = pk2(v.z, v.w);
    d[i] = o;
}

// ---------------------------------------------------------------------------
// 256x256 8-wave 8-phase MFMA GEMM (m201-faithful): per phase
//   { ds_reads for THIS phase's MFMA; stage 1 half-tile; s_barrier;
//     lgkmcnt(0); setprio(1); 16 MFMA; setprio(0); s_barrier }
// Stagger: A-halves of tile t+1 staged at P1/P2 (other buffer); B-halves of
// tile t+2 staged at P3/P4 over B(t)'s slots (dead after P1/P2 reads, barrier
// separated). Single counted vmcnt(4) per K-tile after P4's MFMA: drains
// A(t+1)+B(t+1), leaves B(t+2) in flight. Tail: vmcnt(0) for last 2 tiles.
// Chunk-XOR LDS swizzle (conflict-free, SQ_LDS_BANK_CONFLICT=0 verified).
// Grid: x = N/256 (=4), y = M/256; bijective XCD swizzle (nwg % 8 == 0).
// Multi-segment: sel = bmg>>5 picks weight/bias (QKV fusion).
// ---------------------------------------------------------------------------
template<bool OUT_BF16>
__global__ __launch_bounds__(512) void gemm256_bt(
    const ushort_t* __restrict__ A, const ushort_t* __restrict__ Wbase,
    const float* __restrict__ bias0, const float* __restrict__ bias1,
    const float* __restrict__ bias2, void* __restrict__ Yv,
    int N, int K, float scale0)
{
    __shared__ ushort_t As[2][256 * 64];   // 64 KiB
    __shared__ ushort_t Bs[2][256 * 64];   // 64 KiB

    const int tid  = threadIdx.x;
    const int lane = tid & 63;
    const int w    = tid >> 6;        // 0..7
    const int wm   = w >> 2;          // 0..1 -> 128-row half
    const int wn   = w & 3;           // 0..3 -> 64-col slice
    const int quad = lane >> 4;
    const int l16  = lane & 15;
    const int srow = lane >> 3;       // 0..7 within 8-row segment
    const int sch  = lane & 7;        // chunk slot 0..7

    // bijective XCD-chunked block swizzle
    const int nwg = gridDim.x * gridDim.y;
    const int lin = blockIdx.y * gridDim.x + blockIdx.x;
    const int qq  = nwg >> 3;
    const int swz = (lin & 7) * qq + (lin >> 3);
    const int bn  = swz & 3;          // gridDim.x == 4 (N = 1024)
    const int bmg = swz >> 2;

    const int sel = bmg >> 5;         // 32 blocks per 8192-row segment
    const ushort_t* Wb = Wbase + (size_t)sel * N * K;
    const float* bias = (sel == 0) ? bias0 : (sel == 1) ? bias1 : bias2;
    const float scale = (sel == 0) ? scale0 : 1.0f;

    const size_t arow0 = (size_t)bmg * 256;
    const size_t brow0 = (size_t)bn * 256;
    const int scol = (sch ^ srow) * 8;       // pre-swizzled source chunk

    // per-(half,seg) staging base offsets (elements)
    size_t aoff[2][2], boff[2][2];
#pragma unroll
    for (int h = 0; h < 2; h++)
#pragma unroll
        for (int u = 0; u < 2; u++) {
            const int rl = h * 128 + (w * 2 + u) * 8 + srow;
            aoff[h][u] = (arow0 + rl) * (size_t)K + scol;
            boff[h][u] = (brow0 + rl) * (size_t)K + scol;
        }

    // frag-read chunk offsets: ks=0 -> c0, ks=1 -> c0^32
    const int c0 = (quad ^ (l16 & 7)) * 8;
    const int c1 = c0 ^ 32;

    const f32x4 zero4 = {0.f, 0.f, 0.f, 0.f};
    f32x4 acc[8][4];
#pragma unroll
    for (int i = 0; i < 8; i++)
#pragma unroll
        for (int j = 0; j < 4; j++) acc[i][j] = zero4;

    short8 a0[4][2], a1[4][2];      // A row-half frags [ii][ks]
    short8 b0[2][2], b1[2][2];      // B col-half frags [jj][ks]

    const int nT = K >> 6;  // 16

#define STAGE_A(t, buf, h)                                                  \
    do {                                                                    \
        G2L16(A + aoff[h][0] + (t) * 64,                                    \
              (char*)&As[buf][0] + (h) * 16384 + (w * 2 + 0) * 1024);       \
        G2L16(A + aoff[h][1] + (t) * 64,                                    \
              (char*)&As[buf][0] + (h) * 16384 + (w * 2 + 1) * 1024);       \
    } while (0)
#define STAGE_B(t, buf, h)                                                  \
    do {                                                                    \
        G2L16(Wb + boff[h][0] + (t) * 64,                                   \
              (char*)&Bs[buf][0] + (h) * 16384 + (w * 2 + 0) * 1024);       \
        G2L16(Wb + boff[h][1] + (t) * 64,                                   \
              (char*)&Bs[buf][0] + (h) * 16384 + (w * 2 + 1) * 1024);       \
    } while (0)

    // ---- prologue: tile0 all 4 halves + tile1 B-halves; prime vmcnt ----
    STAGE_A(0, 0, 0); STAGE_A(0, 0, 1);
    STAGE_B(0, 0, 0); STAGE_B(0, 0, 1);
    STAGE_B(1, 1, 0); STAGE_B(1, 1, 1);
    asm volatile("s_waitcnt vmcnt(4)" ::: "memory");   // tile0 landed; B(1) in flight
    SBAR();

    for (int kt = 0; kt < nT; ++kt) {
        const int cur = kt & 1;

        // ---- P1: reads A0+B0; stage A-half0(kt+1); MFMA Q(0,0) ----
#pragma unroll
        for (int ii = 0; ii < 4; ii++) {
            const int row = wm * 128 + ii * 16 + l16;
            a0[ii][0] = *(const short8*)&As[cur][row * 64 + c0];
            a0[ii][1] = *(const short8*)&As[cur][row * 64 + c1];
        }
#pragma unroll
        for (int jj = 0; jj < 2; jj++) {
            const int row = wn * 64 + jj * 16 + l16;
            b0[jj][0] = *(const short8*)&Bs[cur][row * 64 + c0];
            b0[jj][1] = *(const short8*)&Bs[cur][row * 64 + c1];
        }
        if (kt + 1 < nT) STAGE_A(kt + 1, cur ^ 1, 0);
        SBAR();
        LGKM0();
        __builtin_amdgcn_s_setprio(1);
#pragma unroll
        for (int ii = 0; ii < 4; ii++)
#pragma unroll
            for (int jj = 0; jj < 2; jj++)
#pragma unroll
                for (int ks = 0; ks < 2; ks++)
                    acc[ii][jj] = __builtin_amdgcn_mfma_f32_16x16x32_bf16(
                        a0[ii][ks], b0[jj][ks], acc[ii][jj], 0, 0, 0);
        __builtin_amdgcn_s_setprio(0);
        SBAR();

        // ---- P2: reads B1; stage A-half1(kt+1); MFMA Q(0,1) ----
#pragma unroll
        for (int jj = 0; jj < 2; jj++) {
            const int row = wn * 64 + 32 + jj * 16 + l16;
            b1[jj][0] = *(const short8*)&Bs[cur][row * 64 + c0];
            b1[jj][1] = *(const short8*)&Bs[cur][row * 64 + c1];
        }
        if (kt + 1 < nT) STAGE_A(kt + 1, cur ^ 1, 1);
        SBAR();
        LGKM0();
        __builtin_amdgcn_s_setprio(1);
#pragma unroll
        for (int ii = 0; ii < 4; ii++)
#pragma unroll
            for (int jj = 0; jj < 2; jj++)
#pragma unroll
                for (int ks = 0; ks < 2; ks++)
                    acc[ii][2 + jj] = __builtin_amdgcn_mfma_f32_16x16x32_bf16(
                        a0[ii][ks], b1[jj][ks], acc[ii][2 + jj], 0, 0, 0);
        __builtin_amdgcn_s_setprio(0);
        SBAR();

        // ---- P3: reads A1; stage B-half0(kt+2) over dead B(kt)h0; MFMA Q(1,0) ----
#pragma unroll
        for (int ii = 0; ii < 4; ii++) {
            const int row = wm * 128 + 64 + ii * 16 + l16;
            a1[ii][0] = *(const short8*)&As[cur][row * 64 + c0];
            a1[ii][1] = *(const short8*)&As[cur][row * 64 + c1];
        }
        if (kt + 2 < nT) STAGE_B(kt + 2, cur, 0);
        SBAR();
        LGKM0();
        __builtin_amdgcn_s_setprio(1);
#pragma unroll
        for (int ii = 0; ii < 4; ii++)
#pragma unroll
            for (int jj = 0; jj < 2; jj++)
#pragma unroll
                for (int ks = 0; ks < 2; ks++)
                    acc[4 + ii][jj] = __builtin_amdgcn_mfma_f32_16x16x32_bf16(
                        a1[ii][ks], b0[jj][ks], acc[4 + ii][jj], 0, 0, 0);
        __builtin_amdgcn_s_setprio(0);
        SBAR();

        // ---- P4: stage B-half1(kt+2); MFMA Q(1,1); counted vmcnt ----
        if (kt + 2 < nT) STAGE_B(kt + 2, cur, 1);
        SBAR();
        __builtin_amdgcn_s_setprio(1);
#pragma unroll
        for (int ii = 0; ii < 4; ii++)
#pragma unroll
            for (int jj = 0; jj < 2; jj++)
#pragma unroll
                for (int ks = 0; ks < 2; ks++)
                    acc[4 + ii][2 + jj] = __builtin_amdgcn_mfma_f32_16x16x32_bf16(
                        a1[ii][ks], b1[jj][ks], acc[4 + ii][2 + jj], 0, 0, 0);
        __builtin_amdgcn_s_setprio(0);
        if (kt < nT - 2) asm volatile("s_waitcnt vmcnt(4)" ::: "memory");
        else             asm volatile("s_waitcnt vmcnt(0)" ::: "memory");
        SBAR();
    }
#undef STAGE_A
#undef STAGE_B

    // ---- epilogue: bias + scale, store ----
    float bj[4];
#pragma unroll
    for (int j = 0; j < 4; j++) bj[j] = bias[bn * 256 + wn * 64 + j * 16 + l16];
#pragma unroll
    for (int il = 0; il < 8; il++) {
#pragma unroll
        for (int r = 0; r < 4; r++) {
            const size_t row = (size_t)bmg * 256 + wm * 128 + il * 16 + quad * 4 + r;
#pragma unroll
            for (int j = 0; j < 4; j++) {
                const int col = bn * 256 + wn * 64 + j * 16 + l16;
                const float v = (acc[il][j][r] + bj[j]) * scale;
                if (OUT_BF16) ((ushort_t*)Yv)[row * N + col] = f2bf(v);
                else          ((float*)   Yv)[row * N + col] = v;
            }
        }
    }
}

// ---------------------------------------------------------------------------
// Proven 128x128 4-wave MFMA GEMM (round-1 measured): used for O-proj, where
// 256-tiles would give only 128 blocks (half the CUs idle). 512 blocks here.
// ---------------------------------------------------------------------------
template<bool OUT_BF16>
__global__ __launch_bounds__(256) void gemm_bt_mfma(
    const ushort_t* __restrict__ A, const ushort_t* __restrict__ Wbase,
    const float* __restrict__ bias0, const float* __restrict__ bias1,
    const float* __restrict__ bias2, void* __restrict__ Yv,
    int N, int K, float scale0)
{
    __shared__ ushort_t As[128 * 64];
    __shared__ ushort_t Bs[128 * 64];

    const int tid  = threadIdx.x;
    const int lane = tid & 63;
    const int quad = lane >> 4;
    const int l16  = lane & 15;
    const int w    = tid >> 6;
    const int wm   = w >> 1;
    const int wn   = w & 1;
    const int bn   = blockIdx.x;
    const int bmg  = blockIdx.y;

    const int sel = bmg >> 6;                 // 0..2 for QKV, 0 for O-proj
    const ushort_t* Wb = Wbase + (size_t)sel * N * K;
    const float* bias = (sel == 0) ? bias0 : (sel == 1) ? bias1 : bias2;
    const float scale = (sel == 0) ? scale0 : 1.0f;

    const int srow_in = lane >> 3;
    const int sch     = lane & 7;

    const f32x4 zero4 = {0.f, 0.f, 0.f, 0.f};
    f32x4 acc[4][4];
#pragma unroll
    for (int i = 0; i < 4; i++)
#pragma unroll
        for (int j = 0; j < 4; j++) acc[i][j] = zero4;

    for (int k0 = 0; k0 < K; k0 += 64) {
        __syncthreads();
#pragma unroll
        for (int u = 0; u < 4; u++) {
            int seg = w * 4 + u;
            int row = seg * 8 + srow_in;
            int chs = sch ^ (row & 7);
            G2L16(&A [(size_t)(bmg * 128 + row) * K + k0 + chs * 8],
                  (char*)As + seg * 1024);
            G2L16(&Wb[(size_t)(bn  * 128 + row) * K + k0 + chs * 8],
                  (char*)Bs + seg * 1024);
        }
        __syncthreads();

#pragma unroll
        for (int ks = 0; ks < 2; ks++) {
            short8 af[4], bfr[4];
#pragma unroll
            for (int i = 0; i < 4; i++) {
                int row = wm * 64 + i * 16 + l16;
                af[i] = *(const short8*)&As[row * 64 + (((ks * 4 + quad) ^ (row & 7)) * 8)];
            }
#pragma unroll
            for (int j = 0; j < 4; j++) {
                int row = wn * 64 + j * 16 + l16;
                bfr[j] = *(const short8*)&Bs[row * 64 + (((ks * 4 + quad) ^ (row & 7)) * 8)];
            }
#pragma unroll
            for (int i = 0; i < 4; i++)
#pragma unroll
                for (int j = 0; j < 4; j++)
                    acc[i][j] = __builtin_amdgcn_mfma_f32_16x16x32_bf16(
                        af[i], bfr[j], acc[i][j], 0, 0, 0);
        }
    }

    float bj[4];
#pragma unroll
    for (int j = 0; j < 4; j++) bj[j] = bias[bn * 128 + wn * 64 + j * 16 + l16];
#pragma unroll
    for (int i = 0; i < 4; i++) {
#pragma unroll
        for (int r = 0; r < 4; r++) {
            size_t row = (size_t)(bmg * 128 + wm * 64 + i * 16 + quad * 4 + r);
#pragma unroll
            for (int j = 0; j < 4; j++) {
                int col = bn * 128 + wn * 64 + j * 16 + l16;
                float v = (acc[i][j][r] + bj[j]) * scale;
                if (OUT_BF16) ((ushort_t*)Yv)[row * N + col] = f2bf(v);
                else          ((float*)   Yv)[row * N + col] = v;
            }
        }
    }
}

// ---------------------------------------------------------------------------
// Vp (T,B,H,HD) bf16 -> Vt (B,H,HD,T) bf16  (64x64 tiles through LDS)
// ---------------------------------------------------------------------------
__global__ __launch_bounds__(256) void transpose_v(
    const ushort_t* __restrict__ Vp, ushort_t* __restrict__ Vt)
{
    __shared__ ushort_t Ts[64][72];
    const int tid = threadIdx.x;
    const int t0 = blockIdx.x * 64;
    const int bh = blockIdx.y;
    const int b = bh >> 4, h = bh & 15;

#pragma unroll
    for (int u = 0; u < 2; u++) {
        int e = u * 256 + tid;          // 512 chunks of 8 bf16
        int row = e >> 3, ch = (e & 7) * 8;
        uint4 v = *(const uint4*)&Vp[((size_t)(t0 + row) * BATCH + b) * DMODEL + h * 64 + ch];
        *(uint4*)&Ts[row][ch] = v;
    }
    __syncthreads();
#pragma unroll
    for (int u = 0; u < 2; u++) {
        int e = u * 256 + tid;
        int d = e >> 3, tc = (e & 7) * 8;
        uint4 o;
        o.x = (unsigned)Ts[tc + 0][d] | ((unsigned)Ts[tc + 1][d] << 16);
        o.y = (unsigned)Ts[tc + 2][d] | ((unsigned)Ts[tc + 3][d] << 16);
        o.z = (unsigned)Ts[tc + 4][d] | ((unsigned)Ts[tc + 5][d] << 16);
        o.w = (unsigned)Ts[tc + 6][d] | ((unsigned)Ts[tc + 7][d] << 16);
        *(uint4*)&Vt[((size_t)(bh * 64 + d)) * T_SEQ + t0 + tc] = o;
    }
}

// ---------------------------------------------------------------------------
// MFMA flash attention, S^T formulation (unchanged this round).
// ---------------------------------------------------------------------------
__global__ __launch_bounds__(256) void attn_mfma(
    const ushort_t* __restrict__ Qp, const ushort_t* __restrict__ Kp,
    const ushort_t* __restrict__ VtG, ushort_t* __restrict__ Ao)
{
    __shared__ ushort_t Ks[64 * 64];     // [s][hd], 128B rows, 8 chunks, swizzled
    __shared__ ushort_t Vs[64 * 64];     // [hd][s], same structure
    __shared__ ushort_t Pl[4][32][72];   // per-wave P / O-bounce, pitch 72

    const int tid  = threadIdx.x;
    const int lane = tid & 63;
    const int w    = tid >> 6;
    const int quad = lane >> 4;
    const int l16  = lane & 15;
    const int bid  = blockIdx.x;
    const int qb   = bid >> 7;          // 0..7
    const int bh   = bid & 127;
    const int b    = bh >> 4, h = bh & 15;
    const int hoff = h * 64;
    const int q0   = qb * 128 + w * 32;  // this wave's 32 Q rows

    const int srow_in = lane >> 3;       // 0..7 within 8-row segment
    const int sch     = lane & 7;

    // Q fragments (B-operand; same layout as A), in registers all kernel
    short8 qf[2][2];
#pragma unroll
    for (int rt = 0; rt < 2; rt++)
#pragma unroll
        for (int ks = 0; ks < 2; ks++)
            qf[rt][ks] = *(const short8*)&Qp[((size_t)(q0 + rt * 16 + l16) * BATCH + b) * DMODEL
                                             + hoff + ks * 32 + quad * 8];

    short8 ones;
#pragma unroll
    for (int i = 0; i < 8; i++) ones[i] = (short)0x3F80;   // bf16 1.0

    const f32x4 zero4 = {0.f, 0.f, 0.f, 0.f};
    f32x4 oacc[2][4], lacc[2];
#pragma unroll
    for (int rt = 0; rt < 2; rt++) {
        lacc[rt] = zero4;
#pragma unroll
        for (int c = 0; c < 4; c++) oacc[rt][c] = zero4;
    }

    for (int s0 = 0; s0 < T_SEQ; s0 += 64) {
        __syncthreads();   // prev iteration done reading Ks/Vs
#pragma unroll
        for (int u = 0; u < 2; u++) {
            int seg = w * 2 + u;                 // 0..7
            int row = seg * 8 + srow_in;         // 0..63
            int chs = sch ^ (row & 7);
            G2L16(&Kp[((size_t)(s0 + row) * BATCH + b) * DMODEL + hoff + chs * 8],
                  (char*)Ks + seg * 1024);
            G2L16(&VtG[((size_t)(bh * 64 + row)) * T_SEQ + s0 + chs * 8],
                  (char*)Vs + seg * 1024);
        }
        __syncthreads();   // DMA drained

        // ---- S^T = K . Q^T : per c-tile D[m=s in c*16..][n=q] ----
        f32x4 sacc[2][4];
#pragma unroll
        for (int rt = 0; rt < 2; rt++)
#pragma unroll
            for (int c = 0; c < 4; c++) sacc[rt][c] = zero4;
#pragma unroll
        for (int c = 0; c < 4; c++) {
            int row = c * 16 + l16;
#pragma unroll
            for (int ks = 0; ks < 2; ks++) {
                short8 kf = *(const short8*)&Ks[row * 64 + (((ks * 4 + quad) ^ (row & 7)) * 8)];
#pragma unroll
                for (int rt = 0; rt < 2; rt++)
                    sacc[rt][c] = __builtin_amdgcn_mfma_f32_16x16x32_bf16(
                        kf, qf[rt][ks], sacc[rt][c], 0, 0, 0);
            }
        }

        // ---- P = exp2(S): packed b64 writes, already B-fragment layout ----
#pragma unroll
        for (int rt = 0; rt < 2; rt++)
#pragma unroll
            for (int c = 0; c < 4; c++) {
                uint2 pv;
                pv.x = pk2(EXP2F(sacc[rt][c][0]), EXP2F(sacc[rt][c][1]));
                pv.y = pk2(EXP2F(sacc[rt][c][2]), EXP2F(sacc[rt][c][3]));
                *(uint2*)&Pl[w][rt * 16 + l16][c * 16 + quad * 4] = pv;
            }

        short8 pf[2][2];
#pragma unroll
        for (int rt = 0; rt < 2; rt++)
#pragma unroll
            for (int ks = 0; ks < 2; ks++)
                pf[rt][ks] = *(const short8*)&Pl[w][rt * 16 + l16][ks * 32 + quad * 8];

        // ---- denominator: lacc[n=q] += sum_s P[q][s] ----
#pragma unroll
        for (int rt = 0; rt < 2; rt++)
#pragma unroll
            for (int ks = 0; ks < 2; ks++)
                lacc[rt] = __builtin_amdgcn_mfma_f32_16x16x32_bf16(
                    ones, pf[rt][ks], lacc[rt], 0, 0, 0);

        // ---- O^T += V^T . P^T : D[m=d][n=q] ----
#pragma unroll
        for (int dt = 0; dt < 4; dt++) {
            int row = dt * 16 + l16;
#pragma unroll
            for (int ks = 0; ks < 2; ks++) {
                short8 vf = *(const short8*)&Vs[row * 64 + (((ks * 4 + quad) ^ (row & 7)) * 8)];
#pragma unroll
                for (int rt = 0; rt < 2; rt++)
                    oacc[rt][dt] = __builtin_amdgcn_mfma_f32_16x16x32_bf16(
                        vf, pf[rt][ks], oacc[rt][dt], 0, 0, 0);
            }
        }
    }

    // ---- normalize (per-lane, no shuffles), bounce through Pl, store ----
#pragma unroll
    for (int rt = 0; rt < 2; rt++) {
        float inv = 1.f / lacc[rt][0];   // all 4 regs identical (A=ones)
#pragma unroll
        for (int dt = 0; dt < 4; dt++) {
            uint2 ov;
            ov.x = pk2(oacc[rt][dt][0] * inv, oacc[rt][dt][1] * inv);
            ov.y = pk2(oacc[rt][dt][2] * inv, oacc[rt][dt][3] * inv);
            *(uint2*)&Pl[w][rt * 16 + l16][dt * 16 + quad * 4] = ov;
        }
    }
    // coalesced 16B stores: 8 lanes cover one 128B row
#pragma unroll
    for (int it = 0; it < 4; it++) {
        int row = it * 8 + (lane >> 3);
        int ch  = lane & 7;
        uint4 val = *(const uint4*)&Pl[w][row][ch * 8];
        *(uint4*)&Ao[((size_t)(q0 + row) * BATCH + b) * DMODEL + hoff + ch * 8] = val;
    }
}

// ---------------------------------------------------------------------------
extern "C" void kernel_launch(void* const* d_in, const int* in_sizes, int n_in,
                              void* d_out, int out_size, void* d_ws, size_t ws_size,
                              hipStream_t stream)
{
    const float* q  = (const float*)d_in[0];
    const float* k  = (const float*)d_in[1];
    const float* v  = (const float*)d_in[2];
    const float* Wq = (const float*)d_in[3];
    const float* bq = (const float*)d_in[4];
    const float* Wk = (const float*)d_in[5];
    const float* bk = (const float*)d_in[6];
    const float* Wv = (const float*)d_in[7];
    const float* bv = (const float*)d_in[8];
    const float* Wo = (const float*)d_in[9];
    const float* bo = (const float*)d_in[10];

    ushort_t* ws = (ushort_t*)d_ws;
    const size_t E = (size_t)M_ROWS * DMODEL;    // 8388608
    const size_t EW = (size_t)DMODEL * DMODEL;   // 1048576
    ushort_t* qb  = ws;            // input q bf16; reused as Vt
    ushort_t* kb  = ws + E;        // input k bf16; reused as Aob
    ushort_t* vb  = ws + 2 * E;
    ushort_t* Qp  = ws + 3 * E;
    ushort_t* Kp  = ws + 4 * E;
    ushort_t* Vp  = ws + 5 * E;
    ushort_t* Wqb = ws + 6 * E;
    ushort_t* Wkb = Wqb + EW;
    ushort_t* Wvb = Wkb + EW;
    ushort_t* Wob = Wvb + EW;
    ushort_t* Vt  = qb;
    ushort_t* Aob = kb;

    const int n4_in = (int)(E / 4);   // 2097152
    const int n4_w  = (int)(EW / 4);  // 262144
    cast_all_bf16<<<dim3(n4_in / 256, 7), 256, 0, stream>>>(
        (const float4*)q, (const float4*)k, (const float4*)v,
        (const float4*)Wq, (const float4*)Wk, (const float4*)Wv, (const float4*)Wo,
        (uint2*)qb, (uint2*)kb, (uint2*)vb,
        (uint2*)Wqb, (uint2*)Wkb, (uint2*)Wvb, (uint2*)Wob,
        n4_in, n4_w);

    // fused QKV projection: 256-tile 8-phase kernel, M = 3*8192 -> 96 blocks.
    gemm256_bt<true><<<dim3(DMODEL / 256, 3 * M_ROWS / 256), 512, 0, stream>>>(
        qb, Wqb, bq, bk, bv, Qp, DMODEL, DMODEL, QSCALE);

    transpose_v<<<dim3(T_SEQ / 64, BATCH * NHEAD), 256, 0, stream>>>(Vp, Vt);

    attn_mfma<<<dim3(8 * 128), 256, 0, stream>>>(Qp, Kp, Vt, Aob);

    // O-proj: proven 128-tile kernel (512 blocks = 2/CU; 256-tile would idle half)
    gemm_bt_mfma<false><<<dim3(DMODEL / 128, M_ROWS / 128), 256, 0, stream>>>(
        Aob, Wob, bo, bo, bo, d_out, DMODEL, DMODEL, 1.0f);
}